// Round 12
// baseline (282.238 us; speedup 1.0000x reference)
//
#include <hip/hip_runtime.h>
#include <hip/hip_fp16.h>

#define NN 100000
#define NE 1600000
#define KDIM 128

// bucket partition parameters: 256 nodes per bucket
#define BSH 8
#define NBKT ((NN + 255) >> BSH)   // 391
#define BCAP 6144                  // global slab capacity per bucket
#define CHUNK 2048                 // edges per partition block (2x blocks vs 4096)
#define CPAD 16                    // bucket_cursor stride (u32)

// packed edge: src in bits [0,17), dst&255 in bits [17,25)
#define SRC_MASK 0x1FFFFu

#define CVT_BLOCKS (NN * KDIM / 8 / 256)  // 6250

typedef _Float16 half8 __attribute__((ext_vector_type(8)));
typedef float f32x4 __attribute__((ext_vector_type(4)));

// ---------------- pack W[128,NOUT] fp32 -> MFMA B-fragment order, fp16 ----------------
template <int NOUT>
__device__ inline void packW_body(const float* __restrict__ W, _Float16* __restrict__ Wp,
                                  int blk) {
    constexpr int NT = NOUT / 16;
    int idx = blk * 256 + threadIdx.x;
    if (idx >= 128 * NOUT) return;
    int j = idx & 7;
    int l = (idx >> 3) & 63;
    int rest = idx >> 9;
    int nt = rest % NT;
    int kt = rest / NT;
    int k = kt * 32 + ((l >> 4) & 3) * 8 + j;
    int n = nt * 16 + (l & 15);
    Wp[idx] = (_Float16)W[(size_t)k * NOUT + n];
}

// ---------------- fused prep: packW x3 + cursor inits + feat->fp16 (one launch) -------
__global__ __launch_bounds__(256) void k_prep(const float* __restrict__ W1,
                                              const float* __restrict__ W2,
                                              const float* __restrict__ W3,
                                              _Float16* __restrict__ Wp1,
                                              _Float16* __restrict__ Wp2,
                                              _Float16* __restrict__ Wp3,
                                              unsigned* __restrict__ cursor_d,
                                              unsigned* __restrict__ cursor_s,
                                              const float* __restrict__ f,
                                              __half* __restrict__ o) {
    int b = blockIdx.x;
    if (b < 64) packW_body<128>(W1, Wp1, b);
    else if (b < 128) packW_body<128>(W2, Wp2, b - 64);
    else if (b < 160) packW_body<64>(W3, Wp3, b - 128);
    else if (b == 160) {
        for (int k = threadIdx.x; k < NBKT; k += 256) {
            cursor_d[(size_t)k * CPAD] = (unsigned)k * BCAP;
            cursor_s[(size_t)k * CPAD] = (unsigned)k * BCAP;
        }
    } else {
        int i = (b - 161) * 256 + threadIdx.x;
        if (i < NN * KDIM / 8) {
            const float4* f4 = (const float4*)f + 2 * (size_t)i;
            float4 a = f4[0], bb = f4[1];
            __half2 h0 = __floats2half2_rn(a.x, a.y);
            __half2 h1 = __floats2half2_rn(a.z, a.w);
            __half2 h2 = __floats2half2_rn(bb.x, bb.y);
            __half2 h3 = __floats2half2_rn(bb.z, bb.w);
            __half2 hh[4] = {h0, h1, h2, h3};
            *((uint4*)o + i) = *(uint4*)hh;
        }
    }
}

// ---------------- dual partition: dst-keyed (4B payload) + src-keyed (1B payload) ----
// Wave-level two-stage scan (3 barriers instead of 18).
__global__ __launch_bounds__(512) void k_part2(const int* __restrict__ src,
                                               const int* __restrict__ dst,
                                               unsigned* __restrict__ cursor_d,
                                               unsigned* __restrict__ cursor_s,
                                               unsigned* __restrict__ part_d,
                                               unsigned char* __restrict__ part_s) {
    __shared__ unsigned histd[NBKT];  // dst counts -> placement cursor
    __shared__ unsigned hists[NBKT];  // src counts -> placement cursor
    __shared__ unsigned lofsd[NBKT], lofss[NBKT];
    __shared__ unsigned gbased[NBKT], gbases[NBKT];
    __shared__ unsigned wsum[8];
    __shared__ unsigned staged[CHUNK];         // dst-sorted packed edges
    __shared__ unsigned short stagebd[CHUNK];  // dst bucket per staged edge
    __shared__ unsigned char stages[CHUNK];    // src-sorted low bytes
    __shared__ unsigned short stagebs[CHUNK];  // src bucket per staged edge

    const int e0 = blockIdx.x * CHUNK;
    const int lim = min(CHUNK, NE - e0);
    const int t = threadIdx.x;
    const int lane = t & 63;
    const int wv = t >> 6;

    for (int k = t; k < NBKT; k += 512) {
        histd[k] = 0u;
        hists[k] = 0u;
    }
    __syncthreads();

    // pass 1: count both keys (keep edges in registers)
    unsigned es[CHUNK / 512], ed[CHUNK / 512];
    int nmine = 0;
#pragma unroll
    for (int i = 0; i < CHUNK / 512; ++i) {
        int r = t + i * 512;
        if (r < lim) {
            es[i] = (unsigned)src[e0 + r];
            ed[i] = (unsigned)dst[e0 + r];
            atomicAdd(&histd[ed[i] >> BSH], 1u);
            atomicAdd(&hists[es[i] >> BSH], 1u);
            nmine = i + 1;
        }
    }
    __syncthreads();

    // packed two-level wave scan (each field total <= CHUNK < 2^16)
    unsigned vd = (t < NBKT) ? histd[t] : 0u;
    unsigned vs = (t < NBKT) ? hists[t] : 0u;
    unsigned v = (vd << 16) | vs;
    unsigned x = v;
#pragma unroll
    for (int off = 1; off < 64; off <<= 1) {
        unsigned y = __shfl_up(x, off);
        if (lane >= off) x += y;
    }
    if (lane == 63) wsum[wv] = x;
    __syncthreads();
    if (wv == 0) {
        unsigned z = (lane < 8) ? wsum[lane] : 0u;
#pragma unroll
        for (int off = 1; off < 8; off <<= 1) {
            unsigned y = __shfl_up(z, off);
            if (lane >= off) z += y;
        }
        if (lane < 8) wsum[lane] = z;
    }
    __syncthreads();
    unsigned incl = x + (wv ? wsum[wv - 1] : 0u);

    if (t < NBKT) {
        unsigned ld = (incl >> 16) - vd;
        unsigned ls = (incl & 0xFFFFu) - vs;
        lofsd[t] = ld;
        lofss[t] = ls;
        gbased[t] = (vd ? atomicAdd(&cursor_d[(size_t)t * CPAD], vd) : 0u) - ld;
        gbases[t] = (vs ? atomicAdd(&cursor_s[(size_t)t * CPAD], vs) : 0u) - ls;
        histd[t] = 0u;  // reuse as cursors
        hists[t] = 0u;
    }
    __syncthreads();

    // pass 2: place both views into LDS, sorted by bucket
#pragma unroll
    for (int i = 0; i < CHUNK / 512; ++i) {
        if (i < nmine) {
            unsigned kd = ed[i] >> BSH;
            unsigned pd = lofsd[kd] + atomicAdd(&histd[kd], 1u);
            staged[pd] = es[i] | ((ed[i] & 255u) << 17);
            stagebd[pd] = (unsigned short)kd;
            unsigned ks = es[i] >> BSH;
            unsigned ps = lofss[ks] + atomicAdd(&hists[ks], 1u);
            stages[ps] = (unsigned char)(es[i] & 255u);
            stagebs[ps] = (unsigned short)ks;
        }
    }
    __syncthreads();

    // streaming writeout: consecutive j in same bucket -> consecutive global addrs
    for (int j = t; j < lim; j += 512) {
        unsigned k = stagebd[j];
        unsigned gaddr = gbased[k] + (unsigned)j;
        if (gaddr - k * BCAP < BCAP)  // overflow guard (statistically never)
            part_d[gaddr] = staged[j];
        unsigned k2 = stagebs[j];
        unsigned gaddr2 = gbases[k2] + (unsigned)j;
        if (gaddr2 - k2 * BCAP < BCAP)
            part_s[gaddr2] = stages[j];
    }
}

// ---------------- merged CSR build: degrees, norms, row_start, CSR placement --------
__global__ __launch_bounds__(256) void k_build(const unsigned* __restrict__ cursor_d,
                                               const unsigned* __restrict__ cursor_s,
                                               const unsigned* __restrict__ part_d,
                                               const unsigned char* __restrict__ part_s,
                                               unsigned* __restrict__ cnt_in,
                                               float* __restrict__ oi,
                                               float* __restrict__ ii,
                                               unsigned* __restrict__ row_start,
                                               unsigned* __restrict__ csr) {
    __shared__ unsigned c[256];   // in-degree
    __shared__ unsigned c2[256];  // out-degree
    __shared__ unsigned wsum[4];
    __shared__ unsigned cur[256];
    __shared__ unsigned stage[BCAP];
    const int b = blockIdx.x;
    const int t = threadIdx.x;
    const int lane = t & 63;
    const int wv = t >> 6;

    // prefix over bucket totals (from cursors): strided sum + shfl reduction
    unsigned ps = 0;
    for (int k = t; k < b; k += 256)
        ps += min(cursor_d[(size_t)k * CPAD] - (unsigned)k * BCAP, (unsigned)BCAP);
#pragma unroll
    for (int off = 32; off > 0; off >>= 1) ps += __shfl_xor(ps, off);
    if (lane == 0) wsum[wv] = ps;
    c[t] = 0u;
    c2[t] = 0u;
    __syncthreads();
    const unsigned prefix = wsum[0] + wsum[1] + wsum[2] + wsum[3];

    unsigned cntd = min(cursor_d[(size_t)b * CPAD] - (unsigned)b * BCAP, (unsigned)BCAP);
    unsigned cnts = min(cursor_s[(size_t)b * CPAD] - (unsigned)b * BCAP, (unsigned)BCAP);
    const unsigned* ppd = part_d + (size_t)b * BCAP;
    const unsigned char* pps = part_s + (size_t)b * BCAP;
    for (unsigned j = t; j < cntd; j += 256)
        atomicAdd(&c[(ppd[j] >> 17) & 255u], 1u);
    for (unsigned j = t; j < cnts; j += 256)
        atomicAdd(&c2[pps[j]], 1u);
    __syncthreads();

    // two-level wave scan over 256 counts
    unsigned v = c[t];
    unsigned x = v;
#pragma unroll
    for (int off = 1; off < 64; off <<= 1) {
        unsigned y = __shfl_up(x, off);
        if (lane >= off) x += y;
    }
    if (lane == 63) wsum[wv] = x;
    __syncthreads();
    if (wv == 0) {
        unsigned z = (lane < 4) ? wsum[lane] : 0u;
#pragma unroll
        for (int off = 1; off < 4; off <<= 1) {
            unsigned y = __shfl_up(z, off);
            if (lane >= off) z += y;
        }
        if (lane < 4) wsum[lane] = z;
    }
    __syncthreads();
    unsigned incl = x + (wv ? wsum[wv - 1] : 0u);

    int node = (b << BSH) + t;
    if (node < NN) {
        cnt_in[node] = v;
        ii[node] = rsqrtf((float)(v + 1u));
        oi[node] = rsqrtf((float)(c2[t] + 1u));  // deg includes self loop
        row_start[node] = prefix + incl - v;
    }
    cur[t] = incl - v;
    __syncthreads();

    // scatter to stage (part_d now L2-hot), then coalesced writeout
    for (unsigned j = t; j < cntd; j += 256) {
        unsigned e = ppd[j];
        unsigned p = atomicAdd(&cur[(e >> 17) & 255u], 1u);
        stage[p] = e & SRC_MASK;
    }
    __syncthreads();
    for (unsigned j = t; j < cntd; j += 256)
        csr[prefix + j] = stage[j];
}

// ---------------- aggregation, 128-wide fp16 rows: wave per node, fp16 output ------
// predicate-free 16-blocks; masked 16/8 tail sized to remainder.
template <bool SCALE_SRC>
__global__ __launch_bounds__(256) void k_agg128h(const __half* __restrict__ h,
                                                 const float* __restrict__ oi,
                                                 const float* __restrict__ ii,
                                                 const unsigned* __restrict__ row_start,
                                                 const unsigned* __restrict__ cnt_in,
                                                 const unsigned* __restrict__ csr,
                                                 __half* __restrict__ out) {
    int wid = (int)((blockIdx.x * 256u + threadIdx.x) >> 6);
    int lane = threadIdx.x & 63;
    if (wid >= NN) return;
    const __half2* hv = (const __half2*)h;
    float2 acc;
    {
        float2 v = __half22float2(hv[(size_t)wid * 64 + lane]);
        float sc = SCALE_SRC ? oi[wid] : 1.f;  // self loop
        acc.x = v.x * sc;
        acc.y = v.y * sc;
    }
    unsigned rs = row_start[wid];
    unsigned nk = cnt_in[wid];
    for (unsigned base = 0; base < nk; base += 64) {
        unsigned m = min(64u, nk - base);
        unsigned myidx = ((unsigned)lane < m) ? csr[rs + base + lane] : 0u;
        unsigned k = 0;
        for (; k + 16 <= m; k += 16) {
            unsigned s[16];
            float sc[16];
            __half2 v[16];
#pragma unroll
            for (int i = 0; i < 16; ++i) {
                s[i] = (unsigned)__builtin_amdgcn_readlane((int)myidx, (int)(k + i));
                v[i] = hv[(size_t)s[i] * 64 + lane];
                if (SCALE_SRC) sc[i] = oi[s[i]];
            }
#pragma unroll
            for (int i = 0; i < 16; ++i) {
                float2 f = __half22float2(v[i]);
                if (SCALE_SRC) {
                    acc.x = fmaf(f.x, sc[i], acc.x);
                    acc.y = fmaf(f.y, sc[i], acc.y);
                } else {
                    acc.x += f.x;
                    acc.y += f.y;
                }
            }
        }
        unsigned rem = m - k;
        if (rem > 8) {  // masked tail, 9..15 edges
            unsigned s[16];
            float sc[16];
            __half2 v[16];
#pragma unroll
            for (int i = 0; i < 16; ++i) {
                s[i] = (unsigned)__builtin_amdgcn_readlane((int)myidx, (int)(k + i));
                v[i] = hv[(size_t)s[i] * 64 + lane];
                float w = SCALE_SRC ? oi[s[i]] : 1.f;
                sc[i] = (k + i < m) ? w : 0.f;
            }
#pragma unroll
            for (int i = 0; i < 16; ++i) {
                float2 f = __half22float2(v[i]);
                acc.x = fmaf(f.x, sc[i], acc.x);
                acc.y = fmaf(f.y, sc[i], acc.y);
            }
        } else if (rem) {  // masked tail, 1..8 edges
            unsigned s[8];
            float sc[8];
            __half2 v[8];
#pragma unroll
            for (int i = 0; i < 8; ++i) {
                s[i] = (unsigned)__builtin_amdgcn_readlane((int)myidx, (int)(k + i));
                v[i] = hv[(size_t)s[i] * 64 + lane];
                float w = SCALE_SRC ? oi[s[i]] : 1.f;
                sc[i] = (k + i < m) ? w : 0.f;
            }
#pragma unroll
            for (int i = 0; i < 8; ++i) {
                float2 f = __half22float2(v[i]);
                acc.x = fmaf(f.x, sc[i], acc.x);
                acc.y = fmaf(f.y, sc[i], acc.y);
            }
        }
    }
    float si = ii[wid];
    ((__half2*)out)[(size_t)wid * 64 + lane] = __floats2half2_rn(acc.x * si, acc.y * si);
}

// ---------------- aggregation, 64-wide fp16 rows (layer 3: agg after GEMM) ----
__global__ __launch_bounds__(256) void k_agg64h(const __half* __restrict__ t,
                                                const float* __restrict__ ii,
                                                const float* __restrict__ bias,
                                                const unsigned* __restrict__ row_start,
                                                const unsigned* __restrict__ cnt_in,
                                                const unsigned* __restrict__ csr,
                                                float* __restrict__ out) {
    int wid = (int)((blockIdx.x * 256u + threadIdx.x) >> 6);
    int lane = threadIdx.x & 63;
    if (wid >= NN) return;
    float acc = __half2float(t[(size_t)wid * 64 + lane]);  // self loop
    unsigned rs = row_start[wid];
    unsigned nk = cnt_in[wid];
    for (unsigned base = 0; base < nk; base += 64) {
        unsigned m = min(64u, nk - base);
        unsigned myidx = ((unsigned)lane < m) ? csr[rs + base + lane] : 0u;
        unsigned k = 0;
        for (; k + 16 <= m; k += 16) {
            unsigned s[16];
            __half v[16];
#pragma unroll
            for (int i = 0; i < 16; ++i) {
                s[i] = (unsigned)__builtin_amdgcn_readlane((int)myidx, (int)(k + i));
                v[i] = t[(size_t)s[i] * 64 + lane];
            }
#pragma unroll
            for (int i = 0; i < 16; ++i) acc += __half2float(v[i]);
        }
        unsigned rem = m - k;
        if (rem > 8) {
            unsigned s[16];
            float sc[16];
            __half v[16];
#pragma unroll
            for (int i = 0; i < 16; ++i) {
                s[i] = (unsigned)__builtin_amdgcn_readlane((int)myidx, (int)(k + i));
                v[i] = t[(size_t)s[i] * 64 + lane];
                sc[i] = (k + i < m) ? 1.f : 0.f;
            }
#pragma unroll
            for (int i = 0; i < 16; ++i) acc = fmaf(__half2float(v[i]), sc[i], acc);
        } else if (rem) {
            unsigned s[8];
            float sc[8];
            __half v[8];
#pragma unroll
            for (int i = 0; i < 8; ++i) {
                s[i] = (unsigned)__builtin_amdgcn_readlane((int)myidx, (int)(k + i));
                v[i] = t[(size_t)s[i] * 64 + lane];
                sc[i] = (k + i < m) ? 1.f : 0.f;
            }
#pragma unroll
            for (int i = 0; i < 8; ++i) acc = fmaf(__half2float(v[i]), sc[i], acc);
        }
    }
    out[(size_t)wid * 64 + lane] = acc * ii[wid] + bias[lane];
}

// ---------------- layer-1 GEMM, 32 rows/wave: H = relu(A@W1+b1)*oi -> fp16 ----------
__global__ __launch_bounds__(256) void k_gemm1(const _Float16* __restrict__ A,
                                               const _Float16* __restrict__ Wp,
                                               const float* __restrict__ bias,
                                               const float* __restrict__ oscale,
                                               _Float16* __restrict__ Y16) {
    constexpr int NT = 8;
    const int w = threadIdx.x >> 6;
    const int l = threadIdx.x & 63;
    const int r0 = blockIdx.x * 128 + w * 32;
    int arow0 = r0 + (l & 15);
    int arow1 = arow0 + 16;
    if (arow0 >= NN) arow0 = NN - 1;
    if (arow1 >= NN) arow1 = NN - 1;
    const half8* Ap0 = (const half8*)(A + (size_t)arow0 * 128) + (l >> 4);
    const half8* Ap1 = (const half8*)(A + (size_t)arow1 * 128) + (l >> 4);
    const half8* Bp = (const half8*)Wp + l;

    f32x4 acc0[NT], acc1[NT];
#pragma unroll
    for (int n = 0; n < NT; ++n) {
        acc0[n] = {0.f, 0.f, 0.f, 0.f};
        acc1[n] = {0.f, 0.f, 0.f, 0.f};
    }
#pragma unroll
    for (int kt = 0; kt < 4; ++kt) {
        half8 a0 = Ap0[kt * 4];
        half8 a1 = Ap1[kt * 4];
#pragma unroll
        for (int n = 0; n < NT; ++n) {
            half8 b = Bp[(kt * NT + n) * 64];
            acc0[n] = __builtin_amdgcn_mfma_f32_16x16x32_f16(a0, b, acc0[n], 0, 0, 0);
            acc1[n] = __builtin_amdgcn_mfma_f32_16x16x32_f16(a1, b, acc1[n], 0, 0, 0);
        }
    }
    const int col = l & 15;
#pragma unroll
    for (int half = 0; half < 2; ++half) {
        const int rbase = r0 + half * 16 + (l >> 4) * 4;
        f32x4* acc = half ? acc1 : acc0;
#pragma unroll
        for (int j = 0; j < 4; ++j) {
            int row = rbase + j;
            if (row >= NN) continue;
            float os = oscale[row];
#pragma unroll
            for (int n = 0; n < NT; ++n) {
                float v = fmaxf(acc[n][j] + bias[n * 16 + col], 0.f);
                Y16[(size_t)row * 128 + n * 16 + col] = (_Float16)(v * os);
            }
        }
    }
}

// ---------------- fused layers 2+3 GEMM: T = (relu(A@W2+b2)*oi) @ W3 -> fp16 --------
__global__ __launch_bounds__(256) void k_gemm23(const _Float16* __restrict__ A,
                                                const _Float16* __restrict__ Wp2,
                                                const _Float16* __restrict__ Wp3,
                                                const float* __restrict__ bias,
                                                const float* __restrict__ oscale,
                                                _Float16* __restrict__ T16) {
    constexpr int NT = 8;
    __shared__ _Float16 As[4][16][136];  // per-wave 16 x 128 tile, 272B row stride
    const int w = threadIdx.x >> 6;
    const int l = threadIdx.x & 63;
    const int r0 = blockIdx.x * 64 + w * 16;
    int arow = r0 + (l & 15);
    if (arow >= NN) arow = NN - 1;
    const half8* Ap = (const half8*)(A + (size_t)arow * 128) + (l >> 4);
    const half8* Bp2 = (const half8*)Wp2 + l;
    const half8* Bp3 = (const half8*)Wp3 + l;

    // GEMM 2: 16x128 @ 128x128
    f32x4 acc[NT];
#pragma unroll
    for (int n = 0; n < NT; ++n) acc[n] = {0.f, 0.f, 0.f, 0.f};
#pragma unroll
    for (int kt = 0; kt < 4; ++kt) {
        half8 a = Ap[kt * 4];
#pragma unroll
        for (int n = 0; n < NT; ++n) {
            half8 b = Bp2[(kt * NT + n) * 64];
            acc[n] = __builtin_amdgcn_mfma_f32_16x16x32_f16(a, b, acc[n], 0, 0, 0);
        }
    }

    // epilogue 1: bias + relu + oi prescale -> wave-private LDS tile
    const int col = l & 15;
    const int rloc = (l >> 4) * 4;
#pragma unroll
    for (int j = 0; j < 4; ++j) {
        int row = r0 + rloc + j;
        float os = (row < NN) ? oscale[row] : 0.f;
#pragma unroll
        for (int n = 0; n < NT; ++n) {
            float v = fmaxf(acc[n][j] + bias[n * 16 + col], 0.f);
            As[w][rloc + j][n * 16 + col] = (_Float16)(v * os);
        }
    }

    // GEMM 3: 16x128 @ 128x64 (A-frags from LDS; intra-wave, compiler waits lgkmcnt)
    f32x4 acc2[4];
#pragma unroll
    for (int n = 0; n < 4; ++n) acc2[n] = {0.f, 0.f, 0.f, 0.f};
    const int fr = l & 15;
    const int fg = l >> 4;
#pragma unroll
    for (int kt = 0; kt < 4; ++kt) {
        half8 a = *(const half8*)&As[w][fr][kt * 32 + fg * 8];
#pragma unroll
        for (int n = 0; n < 4; ++n) {
            half8 b = Bp3[(kt * 4 + n) * 64];
            acc2[n] = __builtin_amdgcn_mfma_f32_16x16x32_f16(a, b, acc2[n], 0, 0, 0);
        }
    }
#pragma unroll
    for (int j = 0; j < 4; ++j) {
        int row = r0 + rloc + j;
        if (row >= NN) continue;
#pragma unroll
        for (int n = 0; n < 4; ++n)
            T16[(size_t)row * 64 + n * 16 + col] = (_Float16)acc2[n][j];
    }
}

extern "C" void kernel_launch(void* const* d_in, const int* in_sizes, int n_in,
                              void* d_out, int out_size, void* d_ws, size_t ws_size,
                              hipStream_t stream) {
    const float* feat = (const float*)d_in[0];
    const int* src = (const int*)d_in[1];
    const int* dst = (const int*)d_in[2];
    const float* W1 = (const float*)d_in[3];
    const float* b1 = (const float*)d_in[4];
    const float* W2 = (const float*)d_in[5];
    const float* b2 = (const float*)d_in[6];
    const float* W3 = (const float*)d_in[7];
    const float* b3 = (const float*)d_in[8];
    float* out = (float*)d_out;

    char* p = (char*)d_ws;
    auto take = [&](size_t bytes) {
        char* q = p;
        p += (bytes + 255) & ~(size_t)255;
        return q;
    };
    unsigned* cnt_in = (unsigned*)take((size_t)NN * 4);
    float* oi = (float*)take((size_t)NN * 4);
    float* ii = (float*)take((size_t)NN * 4);
    unsigned* row_start = (unsigned*)take((size_t)NN * 4);
    unsigned* cursor_d = (unsigned*)take((size_t)NBKT * CPAD * 4);
    unsigned* cursor_s = (unsigned*)take((size_t)NBKT * CPAD * 4);
    unsigned* csr = (unsigned*)take((size_t)NE * 4);
    unsigned char* part_s = (unsigned char*)take((size_t)NBKT * BCAP);  // 2.4 MB
    __half* feat16 = (__half*)take((size_t)NN * KDIM * 2);
    __half* H16 = (__half*)take((size_t)NN * KDIM * 2);
    __half* G16 = (__half*)take((size_t)NN * KDIM * 2);
    _Float16* Wp1 = (_Float16*)take((size_t)128 * 128 * 2);
    _Float16* Wp2 = (_Float16*)take((size_t)128 * 128 * 2);
    _Float16* Wp3 = (_Float16*)take((size_t)128 * 64 * 2);
    // part_d slab (9.6 MB) / T16 (12.8 MB) share a region: part_d dead after k_build.
    char* regionB = take((size_t)NN * 64 * 2 > (size_t)NBKT * BCAP * 4
                             ? (size_t)NN * 64 * 2
                             : (size_t)NBKT * BCAP * 4);
    unsigned* part_d = (unsigned*)regionB;
    __half* T16 = (__half*)regionB;

    // prep (packW x3 + cursor inits + fp16 convert), dual partition, merged build
    k_prep<<<161 + CVT_BLOCKS, 256, 0, stream>>>(W1, W2, W3, Wp1, Wp2, Wp3, cursor_d,
                                                 cursor_s, feat, feat16);
    k_part2<<<(NE + CHUNK - 1) / CHUNK, 512, 0, stream>>>(src, dst, cursor_d, cursor_s,
                                                          part_d, part_s);
    k_build<<<NBKT, 256, 0, stream>>>(cursor_d, cursor_s, part_d, part_s, cnt_in, oi, ii,
                                      row_start, csr);

    const int AGG_BLOCKS = (NN + 3) / 4;        // 4 waves (nodes) per 256-thread block
    const int GEMM1_BLOCKS = (NN + 127) / 128;  // 32 rows/wave
    const int GEMM23_BLOCKS = (NN + 63) / 64;   // 16 rows/wave

    // layer 1: agg(feat16) -> G16; GEMM(W1)+bias+relu+oi -> H16
    k_agg128h<true><<<AGG_BLOCKS, 256, 0, stream>>>(feat16, oi, ii, row_start, cnt_in, csr, G16);
    k_gemm1<<<GEMM1_BLOCKS, 256, 0, stream>>>((const _Float16*)G16, Wp1, b1, oi,
                                              (_Float16*)H16);
    // layer 2: agg(H16) -> G16; fused GEMM(W2)+bias+relu+oi then GEMM(W3) -> T16
    k_agg128h<false><<<AGG_BLOCKS, 256, 0, stream>>>(H16, oi, ii, row_start, cnt_in, csr, G16);
    k_gemm23<<<GEMM23_BLOCKS, 256, 0, stream>>>((const _Float16*)G16, Wp2, Wp3, b2, oi,
                                                (_Float16*)T16);
    // layer 3 gather: out = ii * (A_hat T) + b3
    k_agg64h<<<AGG_BLOCKS, 256, 0, stream>>>(T16, ii, b3, row_start, cnt_in, csr, out);
}

// Round 13
// 263.599 us; speedup vs baseline: 1.0707x; 1.0707x over previous
//
#include <hip/hip_runtime.h>
#include <hip/hip_fp16.h>

#define NN 100000
#define NE 1600000
#define KDIM 128

// bucket partition parameters: 256 nodes per bucket
#define BSH 8
#define NBKT ((NN + 255) >> BSH)   // 391
#define BCAP 6144                  // global slab capacity per bucket
#define CHUNK 4096                 // edges per partition block
#define CPAD 16                    // bucket_cursor stride (u32)
#define NPART ((NE + CHUNK - 1) / CHUNK)  // 391
#define CVT512 (NN * KDIM / 8 / 512)      // 3125 cvt blocks (512 thr, 8 floats/thr)

// packed edge: src in bits [0,17), dst&255 in bits [17,25)
#define SRC_MASK 0x1FFFFu

typedef _Float16 half8 __attribute__((ext_vector_type(8)));
typedef float f32x4 __attribute__((ext_vector_type(4)));

// ---------------- pack W[128,NOUT] fp32 -> MFMA B-fragment order, fp16 ----------------
template <int NOUT>
__device__ inline void packW_body(const float* __restrict__ W, _Float16* __restrict__ Wp,
                                  int blk) {
    constexpr int NT = NOUT / 16;
    int idx = blk * 256 + threadIdx.x;
    if (idx >= 128 * NOUT) return;
    int j = idx & 7;
    int l = (idx >> 3) & 63;
    int rest = idx >> 9;
    int nt = rest % NT;
    int kt = rest / NT;
    int k = kt * 32 + ((l >> 4) & 3) * 8 + j;
    int n = nt * 16 + (l & 15);
    Wp[idx] = (_Float16)W[(size_t)k * NOUT + n];
}

// ---------------- slim prep: packW x3 + cursor inits (161 blocks, ~3us) --------------
__global__ __launch_bounds__(256) void k_prep(const float* __restrict__ W1,
                                              const float* __restrict__ W2,
                                              const float* __restrict__ W3,
                                              _Float16* __restrict__ Wp1,
                                              _Float16* __restrict__ Wp2,
                                              _Float16* __restrict__ Wp3,
                                              unsigned* __restrict__ cursor_d,
                                              unsigned* __restrict__ cursor_s) {
    int b = blockIdx.x;
    if (b < 64) packW_body<128>(W1, Wp1, b);
    else if (b < 128) packW_body<128>(W2, Wp2, b - 64);
    else if (b < 160) packW_body<64>(W3, Wp3, b - 128);
    else {
        for (int k = threadIdx.x; k < NBKT; k += 256) {
            cursor_d[(size_t)k * CPAD] = (unsigned)k * BCAP;
            cursor_s[(size_t)k * CPAD] = (unsigned)k * BCAP;
        }
    }
}

// ---------------- dual partition + riding fp16 convert (independent work, one launch) -
// Blocks [0,NPART): LDS bucket-sort edges by dst (4B payload) and src (1B payload),
// stream out coalesced runs. Blocks [NPART, NPART+CVT512): feat fp32->fp16 convert.
__global__ __launch_bounds__(512) void k_part2(const int* __restrict__ src,
                                               const int* __restrict__ dst,
                                               unsigned* __restrict__ cursor_d,
                                               unsigned* __restrict__ cursor_s,
                                               unsigned* __restrict__ part_d,
                                               unsigned char* __restrict__ part_s,
                                               const float* __restrict__ f,
                                               __half* __restrict__ o) {
    if (blockIdx.x >= NPART) {  // cvt block: pure streaming, no barriers
        int i = (blockIdx.x - NPART) * 512 + threadIdx.x;
        if (i < NN * KDIM / 8) {
            const float4* f4 = (const float4*)f + 2 * (size_t)i;
            float4 a = f4[0], bb = f4[1];
            __half2 h0 = __floats2half2_rn(a.x, a.y);
            __half2 h1 = __floats2half2_rn(a.z, a.w);
            __half2 h2 = __floats2half2_rn(bb.x, bb.y);
            __half2 h3 = __floats2half2_rn(bb.z, bb.w);
            __half2 hh[4] = {h0, h1, h2, h3};
            *((uint4*)o + i) = *(uint4*)hh;
        }
        return;
    }

    __shared__ unsigned histd[NBKT];  // dst counts -> placement cursor
    __shared__ unsigned hists[NBKT];  // src counts -> placement cursor
    __shared__ unsigned lofsd[NBKT], lofss[NBKT];
    __shared__ unsigned gbased[NBKT], gbases[NBKT];
    __shared__ unsigned wsum[8];
    __shared__ unsigned staged[CHUNK];         // dst-sorted packed edges
    __shared__ unsigned short stagebd[CHUNK];  // dst bucket per staged edge
    __shared__ unsigned char stages[CHUNK];    // src-sorted low bytes
    __shared__ unsigned short stagebs[CHUNK];  // src bucket per staged edge

    const int e0 = blockIdx.x * CHUNK;
    const int lim = min(CHUNK, NE - e0);
    const int t = threadIdx.x;
    const int lane = t & 63;
    const int wv = t >> 6;

    for (int k = t; k < NBKT; k += 512) {
        histd[k] = 0u;
        hists[k] = 0u;
    }
    __syncthreads();

    // pass 1: count both keys (keep edges in registers)
    unsigned es[CHUNK / 512], ed[CHUNK / 512];
    int nmine = 0;
#pragma unroll
    for (int i = 0; i < CHUNK / 512; ++i) {
        int r = t + i * 512;
        if (r < lim) {
            es[i] = (unsigned)src[e0 + r];
            ed[i] = (unsigned)dst[e0 + r];
            atomicAdd(&histd[ed[i] >> BSH], 1u);
            atomicAdd(&hists[es[i] >> BSH], 1u);
            nmine = i + 1;
        }
    }
    __syncthreads();

    // packed two-level wave scan (each field total <= CHUNK < 2^16)
    unsigned vd = (t < NBKT) ? histd[t] : 0u;
    unsigned vs = (t < NBKT) ? hists[t] : 0u;
    unsigned v = (vd << 16) | vs;
    unsigned x = v;
#pragma unroll
    for (int off = 1; off < 64; off <<= 1) {
        unsigned y = __shfl_up(x, off);
        if (lane >= off) x += y;
    }
    if (lane == 63) wsum[wv] = x;
    __syncthreads();
    if (wv == 0) {
        unsigned z = (lane < 8) ? wsum[lane] : 0u;
#pragma unroll
        for (int off = 1; off < 8; off <<= 1) {
            unsigned y = __shfl_up(z, off);
            if (lane >= off) z += y;
        }
        if (lane < 8) wsum[lane] = z;
    }
    __syncthreads();
    unsigned incl = x + (wv ? wsum[wv - 1] : 0u);

    if (t < NBKT) {
        unsigned ld = (incl >> 16) - vd;
        unsigned ls = (incl & 0xFFFFu) - vs;
        lofsd[t] = ld;
        lofss[t] = ls;
        gbased[t] = (vd ? atomicAdd(&cursor_d[(size_t)t * CPAD], vd) : 0u) - ld;
        gbases[t] = (vs ? atomicAdd(&cursor_s[(size_t)t * CPAD], vs) : 0u) - ls;
        histd[t] = 0u;  // reuse as cursors
        hists[t] = 0u;
    }
    __syncthreads();

    // pass 2: place both views into LDS, sorted by bucket
#pragma unroll
    for (int i = 0; i < CHUNK / 512; ++i) {
        if (i < nmine) {
            unsigned kd = ed[i] >> BSH;
            unsigned pd = lofsd[kd] + atomicAdd(&histd[kd], 1u);
            staged[pd] = es[i] | ((ed[i] & 255u) << 17);
            stagebd[pd] = (unsigned short)kd;
            unsigned ks = es[i] >> BSH;
            unsigned ps = lofss[ks] + atomicAdd(&hists[ks], 1u);
            stages[ps] = (unsigned char)(es[i] & 255u);
            stagebs[ps] = (unsigned short)ks;
        }
    }
    __syncthreads();

    // streaming writeout: consecutive j in same bucket -> consecutive global addrs
    for (int j = t; j < lim; j += 512) {
        unsigned k = stagebd[j];
        unsigned gaddr = gbased[k] + (unsigned)j;
        if (gaddr - k * BCAP < BCAP)  // overflow guard (statistically never)
            part_d[gaddr] = staged[j];
        unsigned k2 = stagebs[j];
        unsigned gaddr2 = gbases[k2] + (unsigned)j;
        if (gaddr2 - k2 * BCAP < BCAP)
            part_s[gaddr2] = stages[j];
    }
}

// ---------------- merged CSR build: degrees, norms, row_start, CSR placement --------
__global__ __launch_bounds__(256) void k_build(const unsigned* __restrict__ cursor_d,
                                               const unsigned* __restrict__ cursor_s,
                                               const unsigned* __restrict__ part_d,
                                               const unsigned char* __restrict__ part_s,
                                               unsigned* __restrict__ cnt_in,
                                               float* __restrict__ oi,
                                               float* __restrict__ ii,
                                               unsigned* __restrict__ row_start,
                                               unsigned* __restrict__ csr) {
    __shared__ unsigned c[256];   // in-degree
    __shared__ unsigned c2[256];  // out-degree
    __shared__ unsigned wsum[4];
    __shared__ unsigned cur[256];
    __shared__ unsigned stage[BCAP];
    const int b = blockIdx.x;
    const int t = threadIdx.x;
    const int lane = t & 63;
    const int wv = t >> 6;

    // prefix over bucket totals (from cursors): strided sum + shfl reduction
    unsigned ps = 0;
    for (int k = t; k < b; k += 256)
        ps += min(cursor_d[(size_t)k * CPAD] - (unsigned)k * BCAP, (unsigned)BCAP);
#pragma unroll
    for (int off = 32; off > 0; off >>= 1) ps += __shfl_xor(ps, off);
    if (lane == 0) wsum[wv] = ps;
    c[t] = 0u;
    c2[t] = 0u;
    __syncthreads();
    const unsigned prefix = wsum[0] + wsum[1] + wsum[2] + wsum[3];

    unsigned cntd = min(cursor_d[(size_t)b * CPAD] - (unsigned)b * BCAP, (unsigned)BCAP);
    unsigned cnts = min(cursor_s[(size_t)b * CPAD] - (unsigned)b * BCAP, (unsigned)BCAP);
    const unsigned* ppd = part_d + (size_t)b * BCAP;
    const unsigned char* pps = part_s + (size_t)b * BCAP;
    for (unsigned j = t; j < cntd; j += 256)
        atomicAdd(&c[(ppd[j] >> 17) & 255u], 1u);
    for (unsigned j = t; j < cnts; j += 256)
        atomicAdd(&c2[pps[j]], 1u);
    __syncthreads();

    // two-level wave scan over 256 counts
    unsigned v = c[t];
    unsigned x = v;
#pragma unroll
    for (int off = 1; off < 64; off <<= 1) {
        unsigned y = __shfl_up(x, off);
        if (lane >= off) x += y;
    }
    if (lane == 63) wsum[wv] = x;
    __syncthreads();
    if (wv == 0) {
        unsigned z = (lane < 4) ? wsum[lane] : 0u;
#pragma unroll
        for (int off = 1; off < 4; off <<= 1) {
            unsigned y = __shfl_up(z, off);
            if (lane >= off) z += y;
        }
        if (lane < 4) wsum[lane] = z;
    }
    __syncthreads();
    unsigned incl = x + (wv ? wsum[wv - 1] : 0u);

    int node = (b << BSH) + t;
    if (node < NN) {
        cnt_in[node] = v;
        ii[node] = rsqrtf((float)(v + 1u));
        oi[node] = rsqrtf((float)(c2[t] + 1u));  // deg includes self loop
        row_start[node] = prefix + incl - v;
    }
    cur[t] = incl - v;
    __syncthreads();

    // scatter to stage (part_d now L2-hot), then coalesced writeout
    for (unsigned j = t; j < cntd; j += 256) {
        unsigned e = ppd[j];
        unsigned p = atomicAdd(&cur[(e >> 17) & 255u], 1u);
        stage[p] = e & SRC_MASK;
    }
    __syncthreads();
    for (unsigned j = t; j < cntd; j += 256)
        csr[prefix + j] = stage[j];
}

// ---------------- aggregation, 128-wide fp16 rows: wave per node, fp16 output ------
// predicate-free 16-blocks; masked 16/8 tail sized to remainder.
template <bool SCALE_SRC>
__global__ __launch_bounds__(256) void k_agg128h(const __half* __restrict__ h,
                                                 const float* __restrict__ oi,
                                                 const float* __restrict__ ii,
                                                 const unsigned* __restrict__ row_start,
                                                 const unsigned* __restrict__ cnt_in,
                                                 const unsigned* __restrict__ csr,
                                                 __half* __restrict__ out) {
    int wid = (int)((blockIdx.x * 256u + threadIdx.x) >> 6);
    int lane = threadIdx.x & 63;
    if (wid >= NN) return;
    const __half2* hv = (const __half2*)h;
    float2 acc;
    {
        float2 v = __half22float2(hv[(size_t)wid * 64 + lane]);
        float sc = SCALE_SRC ? oi[wid] : 1.f;  // self loop
        acc.x = v.x * sc;
        acc.y = v.y * sc;
    }
    unsigned rs = row_start[wid];
    unsigned nk = cnt_in[wid];
    for (unsigned base = 0; base < nk; base += 64) {
        unsigned m = min(64u, nk - base);
        unsigned myidx = ((unsigned)lane < m) ? csr[rs + base + lane] : 0u;
        unsigned k = 0;
        for (; k + 16 <= m; k += 16) {
            unsigned s[16];
            float sc[16];
            __half2 v[16];
#pragma unroll
            for (int i = 0; i < 16; ++i) {
                s[i] = (unsigned)__builtin_amdgcn_readlane((int)myidx, (int)(k + i));
                v[i] = hv[(size_t)s[i] * 64 + lane];
                if (SCALE_SRC) sc[i] = oi[s[i]];
            }
#pragma unroll
            for (int i = 0; i < 16; ++i) {
                float2 f = __half22float2(v[i]);
                if (SCALE_SRC) {
                    acc.x = fmaf(f.x, sc[i], acc.x);
                    acc.y = fmaf(f.y, sc[i], acc.y);
                } else {
                    acc.x += f.x;
                    acc.y += f.y;
                }
            }
        }
        unsigned rem = m - k;
        if (rem > 8) {  // masked tail, 9..15 edges
            unsigned s[16];
            float sc[16];
            __half2 v[16];
#pragma unroll
            for (int i = 0; i < 16; ++i) {
                s[i] = (unsigned)__builtin_amdgcn_readlane((int)myidx, (int)(k + i));
                v[i] = hv[(size_t)s[i] * 64 + lane];
                float w = SCALE_SRC ? oi[s[i]] : 1.f;
                sc[i] = (k + i < m) ? w : 0.f;
            }
#pragma unroll
            for (int i = 0; i < 16; ++i) {
                float2 f = __half22float2(v[i]);
                acc.x = fmaf(f.x, sc[i], acc.x);
                acc.y = fmaf(f.y, sc[i], acc.y);
            }
        } else if (rem) {  // masked tail, 1..8 edges
            unsigned s[8];
            float sc[8];
            __half2 v[8];
#pragma unroll
            for (int i = 0; i < 8; ++i) {
                s[i] = (unsigned)__builtin_amdgcn_readlane((int)myidx, (int)(k + i));
                v[i] = hv[(size_t)s[i] * 64 + lane];
                float w = SCALE_SRC ? oi[s[i]] : 1.f;
                sc[i] = (k + i < m) ? w : 0.f;
            }
#pragma unroll
            for (int i = 0; i < 8; ++i) {
                float2 f = __half22float2(v[i]);
                acc.x = fmaf(f.x, sc[i], acc.x);
                acc.y = fmaf(f.y, sc[i], acc.y);
            }
        }
    }
    float si = ii[wid];
    ((__half2*)out)[(size_t)wid * 64 + lane] = __floats2half2_rn(acc.x * si, acc.y * si);
}

// ---------------- aggregation, 64-wide fp16 rows (layer 3: agg after GEMM) ----
__global__ __launch_bounds__(256) void k_agg64h(const __half* __restrict__ t,
                                                const float* __restrict__ ii,
                                                const float* __restrict__ bias,
                                                const unsigned* __restrict__ row_start,
                                                const unsigned* __restrict__ cnt_in,
                                                const unsigned* __restrict__ csr,
                                                float* __restrict__ out) {
    int wid = (int)((blockIdx.x * 256u + threadIdx.x) >> 6);
    int lane = threadIdx.x & 63;
    if (wid >= NN) return;
    float acc = __half2float(t[(size_t)wid * 64 + lane]);  // self loop
    unsigned rs = row_start[wid];
    unsigned nk = cnt_in[wid];
    for (unsigned base = 0; base < nk; base += 64) {
        unsigned m = min(64u, nk - base);
        unsigned myidx = ((unsigned)lane < m) ? csr[rs + base + lane] : 0u;
        unsigned k = 0;
        for (; k + 16 <= m; k += 16) {
            unsigned s[16];
            __half v[16];
#pragma unroll
            for (int i = 0; i < 16; ++i) {
                s[i] = (unsigned)__builtin_amdgcn_readlane((int)myidx, (int)(k + i));
                v[i] = t[(size_t)s[i] * 64 + lane];
            }
#pragma unroll
            for (int i = 0; i < 16; ++i) acc += __half2float(v[i]);
        }
        unsigned rem = m - k;
        if (rem > 8) {
            unsigned s[16];
            float sc[16];
            __half v[16];
#pragma unroll
            for (int i = 0; i < 16; ++i) {
                s[i] = (unsigned)__builtin_amdgcn_readlane((int)myidx, (int)(k + i));
                v[i] = t[(size_t)s[i] * 64 + lane];
                sc[i] = (k + i < m) ? 1.f : 0.f;
            }
#pragma unroll
            for (int i = 0; i < 16; ++i) acc = fmaf(__half2float(v[i]), sc[i], acc);
        } else if (rem) {
            unsigned s[8];
            float sc[8];
            __half v[8];
#pragma unroll
            for (int i = 0; i < 8; ++i) {
                s[i] = (unsigned)__builtin_amdgcn_readlane((int)myidx, (int)(k + i));
                v[i] = t[(size_t)s[i] * 64 + lane];
                sc[i] = (k + i < m) ? 1.f : 0.f;
            }
#pragma unroll
            for (int i = 0; i < 8; ++i) acc = fmaf(__half2float(v[i]), sc[i], acc);
        }
    }
    out[(size_t)wid * 64 + lane] = acc * ii[wid] + bias[lane];
}

// ---------------- layer-1 GEMM, 32 rows/wave: H = relu(A@W1+b1)*oi -> fp16 ----------
__global__ __launch_bounds__(256) void k_gemm1(const _Float16* __restrict__ A,
                                               const _Float16* __restrict__ Wp,
                                               const float* __restrict__ bias,
                                               const float* __restrict__ oscale,
                                               _Float16* __restrict__ Y16) {
    constexpr int NT = 8;
    const int w = threadIdx.x >> 6;
    const int l = threadIdx.x & 63;
    const int r0 = blockIdx.x * 128 + w * 32;
    int arow0 = r0 + (l & 15);
    int arow1 = arow0 + 16;
    if (arow0 >= NN) arow0 = NN - 1;
    if (arow1 >= NN) arow1 = NN - 1;
    const half8* Ap0 = (const half8*)(A + (size_t)arow0 * 128) + (l >> 4);
    const half8* Ap1 = (const half8*)(A + (size_t)arow1 * 128) + (l >> 4);
    const half8* Bp = (const half8*)Wp + l;

    f32x4 acc0[NT], acc1[NT];
#pragma unroll
    for (int n = 0; n < NT; ++n) {
        acc0[n] = {0.f, 0.f, 0.f, 0.f};
        acc1[n] = {0.f, 0.f, 0.f, 0.f};
    }
#pragma unroll
    for (int kt = 0; kt < 4; ++kt) {
        half8 a0 = Ap0[kt * 4];
        half8 a1 = Ap1[kt * 4];
#pragma unroll
        for (int n = 0; n < NT; ++n) {
            half8 b = Bp[(kt * NT + n) * 64];
            acc0[n] = __builtin_amdgcn_mfma_f32_16x16x32_f16(a0, b, acc0[n], 0, 0, 0);
            acc1[n] = __builtin_amdgcn_mfma_f32_16x16x32_f16(a1, b, acc1[n], 0, 0, 0);
        }
    }
    const int col = l & 15;
#pragma unroll
    for (int half = 0; half < 2; ++half) {
        const int rbase = r0 + half * 16 + (l >> 4) * 4;
        f32x4* acc = half ? acc1 : acc0;
#pragma unroll
        for (int j = 0; j < 4; ++j) {
            int row = rbase + j;
            if (row >= NN) continue;
            float os = oscale[row];
#pragma unroll
            for (int n = 0; n < NT; ++n) {
                float v = fmaxf(acc[n][j] + bias[n * 16 + col], 0.f);
                Y16[(size_t)row * 128 + n * 16 + col] = (_Float16)(v * os);
            }
        }
    }
}

// ---------------- fused layers 2+3 GEMM: T = (relu(A@W2+b2)*oi) @ W3 -> fp16 --------
__global__ __launch_bounds__(256) void k_gemm23(const _Float16* __restrict__ A,
                                                const _Float16* __restrict__ Wp2,
                                                const _Float16* __restrict__ Wp3,
                                                const float* __restrict__ bias,
                                                const float* __restrict__ oscale,
                                                _Float16* __restrict__ T16) {
    constexpr int NT = 8;
    __shared__ _Float16 As[4][16][136];  // per-wave 16 x 128 tile, 272B row stride
    const int w = threadIdx.x >> 6;
    const int l = threadIdx.x & 63;
    const int r0 = blockIdx.x * 64 + w * 16;
    int arow = r0 + (l & 15);
    if (arow >= NN) arow = NN - 1;
    const half8* Ap = (const half8*)(A + (size_t)arow * 128) + (l >> 4);
    const half8* Bp2 = (const half8*)Wp2 + l;
    const half8* Bp3 = (const half8*)Wp3 + l;

    // GEMM 2: 16x128 @ 128x128
    f32x4 acc[NT];
#pragma unroll
    for (int n = 0; n < NT; ++n) acc[n] = {0.f, 0.f, 0.f, 0.f};
#pragma unroll
    for (int kt = 0; kt < 4; ++kt) {
        half8 a = Ap[kt * 4];
#pragma unroll
        for (int n = 0; n < NT; ++n) {
            half8 b = Bp2[(kt * NT + n) * 64];
            acc[n] = __builtin_amdgcn_mfma_f32_16x16x32_f16(a, b, acc[n], 0, 0, 0);
        }
    }

    // epilogue 1: bias + relu + oi prescale -> wave-private LDS tile
    const int col = l & 15;
    const int rloc = (l >> 4) * 4;
#pragma unroll
    for (int j = 0; j < 4; ++j) {
        int row = r0 + rloc + j;
        float os = (row < NN) ? oscale[row] : 0.f;
#pragma unroll
        for (int n = 0; n < NT; ++n) {
            float v = fmaxf(acc[n][j] + bias[n * 16 + col], 0.f);
            As[w][rloc + j][n * 16 + col] = (_Float16)(v * os);
        }
    }

    // GEMM 3: 16x128 @ 128x64 (A-frags from LDS; intra-wave, compiler waits lgkmcnt)
    f32x4 acc2[4];
#pragma unroll
    for (int n = 0; n < 4; ++n) acc2[n] = {0.f, 0.f, 0.f, 0.f};
    const int fr = l & 15;
    const int fg = l >> 4;
#pragma unroll
    for (int kt = 0; kt < 4; ++kt) {
        half8 a = *(const half8*)&As[w][fr][kt * 32 + fg * 8];
#pragma unroll
        for (int n = 0; n < 4; ++n) {
            half8 b = Bp3[(kt * 4 + n) * 64];
            acc2[n] = __builtin_amdgcn_mfma_f32_16x16x32_f16(a, b, acc2[n], 0, 0, 0);
        }
    }
#pragma unroll
    for (int j = 0; j < 4; ++j) {
        int row = r0 + rloc + j;
        if (row >= NN) continue;
#pragma unroll
        for (int n = 0; n < 4; ++n)
            T16[(size_t)row * 64 + n * 16 + col] = (_Float16)acc2[n][j];
    }
}

extern "C" void kernel_launch(void* const* d_in, const int* in_sizes, int n_in,
                              void* d_out, int out_size, void* d_ws, size_t ws_size,
                              hipStream_t stream) {
    const float* feat = (const float*)d_in[0];
    const int* src = (const int*)d_in[1];
    const int* dst = (const int*)d_in[2];
    const float* W1 = (const float*)d_in[3];
    const float* b1 = (const float*)d_in[4];
    const float* W2 = (const float*)d_in[5];
    const float* b2 = (const float*)d_in[6];
    const float* W3 = (const float*)d_in[7];
    const float* b3 = (const float*)d_in[8];
    float* out = (float*)d_out;

    char* p = (char*)d_ws;
    auto take = [&](size_t bytes) {
        char* q = p;
        p += (bytes + 255) & ~(size_t)255;
        return q;
    };
    unsigned* cnt_in = (unsigned*)take((size_t)NN * 4);
    float* oi = (float*)take((size_t)NN * 4);
    float* ii = (float*)take((size_t)NN * 4);
    unsigned* row_start = (unsigned*)take((size_t)NN * 4);
    unsigned* cursor_d = (unsigned*)take((size_t)NBKT * CPAD * 4);
    unsigned* cursor_s = (unsigned*)take((size_t)NBKT * CPAD * 4);
    unsigned* csr = (unsigned*)take((size_t)NE * 4);
    unsigned char* part_s = (unsigned char*)take((size_t)NBKT * BCAP);  // 2.4 MB
    __half* feat16 = (__half*)take((size_t)NN * KDIM * 2);
    __half* H16 = (__half*)take((size_t)NN * KDIM * 2);
    __half* G16 = (__half*)take((size_t)NN * KDIM * 2);
    _Float16* Wp1 = (_Float16*)take((size_t)128 * 128 * 2);
    _Float16* Wp2 = (_Float16*)take((size_t)128 * 128 * 2);
    _Float16* Wp3 = (_Float16*)take((size_t)128 * 64 * 2);
    // part_d slab (9.6 MB) / T16 (12.8 MB) share a region: part_d dead after k_build.
    char* regionB = take((size_t)NN * 64 * 2 > (size_t)NBKT * BCAP * 4
                             ? (size_t)NN * 64 * 2
                             : (size_t)NBKT * BCAP * 4);
    unsigned* part_d = (unsigned*)regionB;
    __half* T16 = (__half*)regionB;

    // slim prep (packW x3 + cursor inits), partition+cvt combined, merged build
    k_prep<<<161, 256, 0, stream>>>(W1, W2, W3, Wp1, Wp2, Wp3, cursor_d, cursor_s);
    k_part2<<<NPART + CVT512, 512, 0, stream>>>(src, dst, cursor_d, cursor_s, part_d,
                                                part_s, feat, feat16);
    k_build<<<NBKT, 256, 0, stream>>>(cursor_d, cursor_s, part_d, part_s, cnt_in, oi, ii,
                                      row_start, csr);

    const int AGG_BLOCKS = (NN + 3) / 4;        // 4 waves (nodes) per 256-thread block
    const int GEMM1_BLOCKS = (NN + 127) / 128;  // 32 rows/wave
    const int GEMM23_BLOCKS = (NN + 63) / 64;   // 16 rows/wave

    // layer 1: agg(feat16) -> G16; GEMM(W1)+bias+relu+oi -> H16
    k_agg128h<true><<<AGG_BLOCKS, 256, 0, stream>>>(feat16, oi, ii, row_start, cnt_in, csr, G16);
    k_gemm1<<<GEMM1_BLOCKS, 256, 0, stream>>>((const _Float16*)G16, Wp1, b1, oi,
                                              (_Float16*)H16);
    // layer 2: agg(H16) -> G16; fused GEMM(W2)+bias+relu+oi then GEMM(W3) -> T16
    k_agg128h<false><<<AGG_BLOCKS, 256, 0, stream>>>(H16, oi, ii, row_start, cnt_in, csr, G16);
    k_gemm23<<<GEMM23_BLOCKS, 256, 0, stream>>>((const _Float16*)G16, Wp2, Wp3, b2, oi,
                                                (_Float16*)T16);
    // layer 3 gather: out = ii * (A_hat T) + b3
    k_agg64h<<<AGG_BLOCKS, 256, 0, stream>>>(T16, ii, b3, row_start, cnt_in, csr, out);
}